// Round 25
// baseline (212.323 us; speedup 1.0000x reference)
//
#include <hip/hip_runtime.h>

#define DM 1024
#define SEQ 2048
#define NH 16
#define DK 64

typedef __bf16 bf16x8 __attribute__((ext_vector_type(8)));
typedef float f32x4 __attribute__((ext_vector_type(4)));

// softmax scale folded into Q: 1/sqrt(64) * log2(e)
#define QSCALE 0.1803368801111244f

__device__ inline unsigned short f2bf(float f) {
    unsigned u = __float_as_uint(f);
    u += 0x7fffu + ((u >> 16) & 1u);
    return (unsigned short)(u >> 16);
}

__device__ inline unsigned pkbf(float lo, float hi) {
    union { __bf16 h[2]; unsigned u; } r;
    r.h[0] = (__bf16)lo; r.h[1] = (__bf16)hi;
    return r.u;
}

// fp32 -> bf16 for the four weight matrices (1M elems each), one dispatch.
__global__ __launch_bounds__(256) void cvt_w(const float* __restrict__ s0,
                                             const float* __restrict__ s1,
                                             const float* __restrict__ s2,
                                             const float* __restrict__ s3,
                                             unsigned short* __restrict__ d0,
                                             unsigned short* __restrict__ d1,
                                             unsigned short* __restrict__ d2,
                                             unsigned short* __restrict__ d3) {
    const float* s;
    unsigned short* d;
    switch (blockIdx.y) {
        case 0: s = s0; d = d0; break;
        case 1: s = s1; d = d1; break;
        case 2: s = s2; d = d2; break;
        default: s = s3; d = d3; break;
    }
    int i = (blockIdx.x * 256 + threadIdx.x) * 4;
    float4 v = *(const float4*)(s + i);
    ushort4 o;
    o.x = f2bf(v.x); o.y = f2bf(v.y); o.z = f2bf(v.z); o.w = f2bf(v.w);
    *(ushort4*)(d + i) = o;
}

// Merged Q/K/V projection GEMM: 1536 blocks (seg = bid>>9), 48KB LDS ->
// 3 blocks/CU, depth-2 A prefetch.
__global__ __launch_bounds__(512) void gemm_qkv(
    const float* __restrict__ Aq, const float* __restrict__ Ak,
    const float* __restrict__ Avv,
    const unsigned short* __restrict__ Wq2, const unsigned short* __restrict__ Wk2,
    const unsigned short* __restrict__ Wv2,
    const float* __restrict__ bq2, const float* __restrict__ bk2,
    const float* __restrict__ bv2,
    unsigned short* __restrict__ Cq, unsigned short* __restrict__ Ck,
    unsigned short* __restrict__ Cvt) {
    __shared__ unsigned short lds_a[128 * 64];
    __shared__ unsigned short lds_w[2][128 * 64];

    const int K = DM, N = DM;
    const int t = threadIdx.x;
    const int lane = t & 63;
    const int w = t >> 6;
    const int wr = w >> 1;
    const int wc = w & 1;
    const int seg = blockIdx.x >> 9;      // 0=Q 1=K 2=V
    const int inner = blockIdx.x & 511;
    const int xcd = inner & 7;
    const int idx = inner >> 3;
    const int rowBase = (xcd * 8 + (idx >> 3)) * 128;
    const int colBase = (idx & 7) * 128;
    const int l15 = lane & 15;
    const int lg = lane >> 4;
    const int ar = t >> 2, aq = t & 3;
    const int NIT = K >> 6;  // 16

    const float* A = seg == 0 ? Aq : (seg == 1 ? Ak : Avv);
    const unsigned short* W = seg == 0 ? Wq2 : (seg == 1 ? Wk2 : Wv2);
    const float* bias = seg == 0 ? bq2 : (seg == 1 ? bk2 : bv2);

    f32x4 acc[2][4] = {};

    auto STAGE_W = [&](int kt, int buf) {
#pragma unroll
        for (int i = 0; i < 2; ++i) {
            const int row = (w * 2 + i) * 8 + (lane >> 3);
            const int sl = lane & 7;
            const unsigned short* src =
                W + (size_t)(colBase + row) * K + kt * 64 + ((sl ^ (row & 7)) * 8);
            __builtin_amdgcn_global_load_lds(src, &lds_w[buf][(w * 2 + i) * 512], 16, 0, 0);
        }
    };
    auto LOADA = [&](int kt, float4* rf) {
        const float* Af = A + (size_t)(rowBase + ar) * K + kt * 64 + aq * 16;
#pragma unroll
        for (int i = 0; i < 4; ++i) rf[i] = *(const float4*)(Af + i * 4);
    };
    auto WRITEA = [&](const float4* rf) {
#pragma unroll
        for (int i = 0; i < 2; ++i) {
            union { __bf16 h[8]; uint4 u; } pk;
            pk.h[0] = (__bf16)rf[2 * i].x; pk.h[1] = (__bf16)rf[2 * i].y;
            pk.h[2] = (__bf16)rf[2 * i].z; pk.h[3] = (__bf16)rf[2 * i].w;
            pk.h[4] = (__bf16)rf[2 * i + 1].x; pk.h[5] = (__bf16)rf[2 * i + 1].y;
            pk.h[6] = (__bf16)rf[2 * i + 1].z; pk.h[7] = (__bf16)rf[2 * i + 1].w;
            *(uint4*)&lds_a[ar * 64 + (((aq * 2 + i) ^ (ar & 7)) * 8)] = pk.u;
        }
    };
    auto COMPUTE = [&](int wbuf) {
#pragma unroll
        for (int kh = 0; kh < 2; ++kh) {
            bf16x8 af[2], wf[4];
#pragma unroll
            for (int m = 0; m < 2; ++m)
                af[m] = *(const bf16x8*)&lds_a[(wr * 32 + m * 16 + l15) * 64 +
                                               (((kh * 4 + lg) ^ (l15 & 7)) * 8)];
#pragma unroll
            for (int n = 0; n < 4; ++n)
                wf[n] = *(const bf16x8*)&lds_w[wbuf][(wc * 64 + n * 16 + l15) * 64 +
                                                    (((kh * 4 + lg) ^ (l15 & 7)) * 8)];
#pragma unroll
            for (int m = 0; m < 2; ++m)
#pragma unroll
                for (int n = 0; n < 4; ++n)
                    acc[m][n] = __builtin_amdgcn_mfma_f32_16x16x32_bf16(af[m], wf[n],
                                                                        acc[m][n], 0, 0, 0);
        }
    };

    float4 ra[4], rb[4];
    STAGE_W(0, 0);
    LOADA(0, ra);
    LOADA(1, rb);
    for (int kt = 0; kt < NIT; kt += 2) {
        if (kt + 1 < NIT) {
            STAGE_W(kt + 1, 1);
            asm volatile("s_waitcnt vmcnt(6)" ::: "memory");
        } else {
            asm volatile("s_waitcnt vmcnt(0)" ::: "memory");
        }
        WRITEA(ra);
        if (kt + 2 < NIT) LOADA(kt + 2, ra);
        asm volatile("s_waitcnt lgkmcnt(0)" ::: "memory");
        __builtin_amdgcn_s_barrier();
        COMPUTE(0);
        __builtin_amdgcn_s_barrier();
        if (kt + 2 < NIT) {
            STAGE_W(kt + 2, 0);
            asm volatile("s_waitcnt vmcnt(6)" ::: "memory");
        } else {
            asm volatile("s_waitcnt vmcnt(0)" ::: "memory");
        }
        WRITEA(rb);
        if (kt + 3 < NIT) LOADA(kt + 3, rb);
        asm volatile("s_waitcnt lgkmcnt(0)" ::: "memory");
        __builtin_amdgcn_s_barrier();
        COMPUTE(1);
        __builtin_amdgcn_s_barrier();
    }

    const float oscale = seg == 0 ? QSCALE : 1.0f;
#pragma unroll
    for (int m = 0; m < 2; ++m) {
        int row = rowBase + wr * 32 + m * 16 + lg * 4;
#pragma unroll
        for (int n = 0; n < 4; ++n) {
            int col = colBase + wc * 64 + n * 16 + l15;
            float bv = bias[col];
            if (seg == 2) {
                const int bh = (row >> 11) * NH + (col >> 6);
                const int dloc = col & 63;
                const int s = row & (SEQ - 1);
                ushort4 o;
                o.x = f2bf(acc[m][n][0] + bv);
                o.y = f2bf(acc[m][n][1] + bv);
                o.z = f2bf(acc[m][n][2] + bv);
                o.w = f2bf(acc[m][n][3] + bv);
                *(ushort4*)(Cvt + ((size_t)bh * DK + dloc) * SEQ + s) = o;
            } else {
                unsigned short* C = seg == 0 ? Cq : Ck;
#pragma unroll
                for (int j = 0; j < 4; ++j)
                    C[(size_t)(row + j) * N + col] = f2bf((acc[m][n][j] + bv) * oscale);
            }
        }
    }
}

// Output GEMM: C[8192,1024]f32 = X bf16 @ Wo bf16^T + bo.  Full dbuf, gload_lds.
__global__ __launch_bounds__(512) void gemm_out(const unsigned short* __restrict__ A,
                                                const unsigned short* __restrict__ W,
                                                const float* __restrict__ bias,
                                                float* __restrict__ C) {
    __shared__ unsigned short lds_a[2][128 * 64];
    __shared__ unsigned short lds_w[2][128 * 64];

    const int K = DM, N = DM;
    const int t = threadIdx.x;
    const int lane = t & 63;
    const int w = t >> 6;
    const int wr = w >> 1;
    const int wc = w & 1;
    const int bid = blockIdx.x;
    const int xcd = bid & 7;
    const int idx = bid >> 3;
    const int rowBase = (xcd * 8 + (idx >> 3)) * 128;
    const int colBase = (idx & 7) * 128;
    const int l15 = lane & 15;
    const int lg = lane >> 4;
    const int NIT = K >> 6;

    f32x4 acc[2][4] = {};

    auto STAGE = [&](const unsigned short* M0, unsigned short* ldsb, int kt) {
#pragma unroll
        for (int i = 0; i < 2; ++i) {
            const int row = (w * 2 + i) * 8 + (lane >> 3);
            const int sl = lane & 7;
            const unsigned short* src =
                M0 + (size_t)row * K + kt * 64 + ((sl ^ (row & 7)) * 8);
            __builtin_amdgcn_global_load_lds(src, ldsb + (w * 2 + i) * 512, 16, 0, 0);
        }
    };
    auto COMPUTE = [&](int buf) {
#pragma unroll
        for (int kh = 0; kh < 2; ++kh) {
            bf16x8 af[2], wf[4];
#pragma unroll
            for (int m = 0; m < 2; ++m)
                af[m] = *(const bf16x8*)&lds_a[buf][(wr * 32 + m * 16 + l15) * 64 +
                                                   (((kh * 4 + lg) ^ (l15 & 7)) * 8)];
#pragma unroll
            for (int n = 0; n < 4; ++n)
                wf[n] = *(const bf16x8*)&lds_w[buf][(wc * 64 + n * 16 + l15) * 64 +
                                                   (((kh * 4 + lg) ^ (l15 & 7)) * 8)];
#pragma unroll
            for (int m = 0; m < 2; ++m)
#pragma unroll
                for (int n = 0; n < 4; ++n)
                    acc[m][n] = __builtin_amdgcn_mfma_f32_16x16x32_bf16(af[m], wf[n],
                                                                        acc[m][n], 0, 0, 0);
        }
    };

    const unsigned short* Arow = A + (size_t)rowBase * K;
    const unsigned short* Wrow = W + (size_t)colBase * K;
    STAGE(Wrow, lds_w[0], 0);
    STAGE(Arow, lds_a[0], 0);
    for (int kt = 0; kt < NIT; ++kt) {
        const int cur = kt & 1;
        if (kt + 1 < NIT) {
            STAGE(Wrow, lds_w[cur ^ 1], kt + 1);
            STAGE(Arow, lds_a[cur ^ 1], kt + 1);
            asm volatile("s_waitcnt vmcnt(4)" ::: "memory");
        } else {
            asm volatile("s_waitcnt vmcnt(0)" ::: "memory");
        }
        __builtin_amdgcn_s_barrier();
        COMPUTE(cur);
        __builtin_amdgcn_s_barrier();
    }

#pragma unroll
    for (int m = 0; m < 2; ++m) {
        int row = rowBase + wr * 32 + m * 16 + lg * 4;
#pragma unroll
        for (int n = 0; n < 4; ++n) {
            int col = colBase + wc * 64 + n * 16 + l15;
            float bv = bias[col];
#pragma unroll
            for (int j = 0; j < 4; ++j)
                C[(size_t)(row + j) * N + col] = acc[m][n][j] + bv;
        }
    }
}

// Flash attention, causal, swapped-operand.  512 threads / 8 waves per block,
// 128 q-rows per block sharing each staged 64x64 K/V tile (staging DMA count,
// barrier count, and K/V re-fetch all HALVE vs the 4-wave block).  K/V staged
// via global_load_lds DMA (rule #21 pattern, 1 K + 1 V instr per thread);
// pair-tasking over 16 128-row q-tiles -> 34 uniform steps/block; P via
// wave-private LDS; no online max (exp2 unclamped); ones-row MFMA denominator.
__global__ __launch_bounds__(512) void attn(const unsigned short* __restrict__ Q,
                                            const unsigned short* __restrict__ K,
                                            const unsigned short* __restrict__ Vt,
                                            unsigned short* __restrict__ X) {
    __shared__ unsigned short k_lds[2][64 * 64];
    __shared__ unsigned short v_lds[2][64 * 64];
    __shared__ unsigned short p_lds[8][16 * 64];  // per-wave P^T tile, swizzled

    const int t = threadIdx.x;
    const int lane = t & 63;
    const int w = t >> 6;            // 0..7
    const int l15 = lane & 15, lg = lane >> 4;

    // XCD chunk: 512 blocks, 64/XCD -> 8 bh per XCD (8 pairs each)
    const int orig = blockIdx.x;
    const int flat = (orig & 7) * 64 + (orig >> 3);
    const int bh = flat >> 3;
    const int pr = flat & 7;         // pair id 0..7
    const int b = bh >> 4, h = bh & 15;

    const unsigned short* Qb = Q + (size_t)b * SEQ * DM + h * DK;
    const unsigned short* Kb = K + (size_t)b * SEQ * DM + h * DK;
    const unsigned short* Vb = Vt + (size_t)bh * DK * SEQ;

    const int xork = (l15 & 7) * 8;
    unsigned short* pl = p_lds[w];

    union { unsigned short us[8]; bf16x8 v; } ou;
#pragma unroll
    for (int i = 0; i < 8; ++i) ou.us[i] = 0x3F80;
    const bf16x8 onesf = ou.v;

    int gp = 0;

    // DMA staging: thread -> row = t>>3 (0..63), dest = wave base + lane*16;
    // source col inverse-swizzled so reads stay 0-conflict.
    const int grow = t >> 3;
    const int gcol = ((t & 7) ^ (grow & 7)) * 8;

    auto GLOAD = [&](int kv0, int buf) {
        __builtin_amdgcn_global_load_lds(
            Kb + (size_t)(kv0 + grow) * DM + gcol, &k_lds[buf][w * 512], 16, 0, 0);
        __builtin_amdgcn_global_load_lds(
            Vb + (size_t)grow * SEQ + kv0 + gcol, &v_lds[buf][w * 512], 16, 0, 0);
    };

    GLOAD(0, 0);  // task-0 tile-0

    for (int task = 0; task < 2; ++task) {
        const int qt = task ? 15 - pr : pr;   // 128-row q-tile index 0..15
        const int qrow0 = qt * 128 + w * 16;
        const int qg = qrow0 + l15;

        const bf16x8 qf0 = *(const bf16x8*)(Qb + (size_t)(qrow0 + l15) * DM + lg * 8);
        const bf16x8 qf1 = *(const bf16x8*)(Qb + (size_t)(qrow0 + l15) * DM + lg * 8 + 32);

        f32x4 acc[4] = {};
        f32x4 accS = {};
        const int nt = 2 * qt + 2;   // 64-kv tiles covering the 128-row block

        for (int tile = 0; tile < nt; ++tile) {
            const int kv0 = tile << 6;
            unsigned short* kl = k_lds[gp & 1];
            unsigned short* vl = v_lds[gp & 1];
            // my DMA writes for THIS tile done; barrier makes all waves' visible
            asm volatile("s_waitcnt vmcnt(0)" ::: "memory");
            __syncthreads();

            if (tile + 1 < nt)
                GLOAD((tile + 1) << 6, (gp + 1) & 1);
            else if (task == 0)
                GLOAD(0, (gp + 1) & 1);  // prefetch task-1 tile-0

            f32x4 st[4];
#pragma unroll
            for (int s = 0; s < 4; ++s) {
                const int rb2 = (s * 16 + l15) * 64;
                bf16x8 ka = *(const bf16x8*)&kl[rb2 + ((lg * 8) ^ xork)];
                bf16x8 kb2 = *(const bf16x8*)&kl[rb2 + ((32 + lg * 8) ^ xork)];
                f32x4 z = {};
                z = __builtin_amdgcn_mfma_f32_16x16x32_bf16(ka, qf0, z, 0, 0, 0);
                st[s] = __builtin_amdgcn_mfma_f32_16x16x32_bf16(kb2, qf1, z, 0, 0, 0);
            }

            bf16x8 vf[4][2];
#pragma unroll
            for (int d = 0; d < 4; ++d) {
                const int rb2 = (d * 16 + l15) * 64;
                vf[d][0] = *(const bf16x8*)&vl[rb2 + ((lg * 8) ^ xork)];
                vf[d][1] = *(const bf16x8*)&vl[rb2 + ((32 + lg * 8) ^ xork)];
            }

            // P = exp2(score); masked lanes get 0
            float ps[16];
            if (kv0 + 63 > qrow0) {  // diagonal/above: apply causal mask
#pragma unroll
                for (int s = 0; s < 4; ++s)
#pragma unroll
                    for (int j = 0; j < 4; ++j) {
                        const bool ok = kv0 + s * 16 + 4 * lg + j <= qg;
                        ps[s * 4 + j] = ok ? exp2f(st[s][j]) : 0.0f;
                    }
            } else {
#pragma unroll
                for (int s = 0; s < 4; ++s)
#pragma unroll
                    for (int j = 0; j < 4; ++j)
                        ps[s * 4 + j] = exp2f(st[s][j]);
            }

            // write P[q=l15][kv] to wave-private LDS (slot-swizzled), no barrier
#pragma unroll
            for (int s = 0; s < 4; ++s) {
                uint2 pk;
                pk.x = pkbf(ps[s * 4 + 0], ps[s * 4 + 1]);
                pk.y = pkbf(ps[s * 4 + 2], ps[s * 4 + 3]);
                const int slot = (s * 2 + (lg >> 1)) ^ (l15 & 7);
                *(uint2*)&pl[l15 * 64 + slot * 8 + (lg & 1) * 4] = pk;
            }
            bf16x8 pf[2];
#pragma unroll
            for (int hh = 0; hh < 2; ++hh)
                pf[hh] = *(const bf16x8*)&pl[l15 * 64 + (((hh * 4 + lg) ^ (l15 & 7)) * 8)];

#pragma unroll
            for (int d = 0; d < 4; ++d) {
                acc[d] = __builtin_amdgcn_mfma_f32_16x16x32_bf16(vf[d][0], pf[0], acc[d], 0, 0, 0);
                acc[d] = __builtin_amdgcn_mfma_f32_16x16x32_bf16(vf[d][1], pf[1], acc[d], 0, 0, 0);
            }
            accS = __builtin_amdgcn_mfma_f32_16x16x32_bf16(onesf, pf[0], accS, 0, 0, 0);
            accS = __builtin_amdgcn_mfma_f32_16x16x32_bf16(onesf, pf[1], accS, 0, 0, 0);
            gp++;
        }

        const float inv = 1.0f / accS[0];
#pragma unroll
        for (int d = 0; d < 4; ++d) {
            ushort4 o;
            o.x = f2bf(acc[d][0] * inv);
            o.y = f2bf(acc[d][1] * inv);
            o.z = f2bf(acc[d][2] * inv);
            o.w = f2bf(acc[d][3] * inv);
            *(ushort4*)&X[(size_t)(b * SEQ + qg) * DM + h * DK + d * 16 + 4 * lg] = o;
        }
    }
}

extern "C" void kernel_launch(void* const* d_in, const int* in_sizes, int n_in,
                              void* d_out, int out_size, void* d_ws, size_t ws_size,
                              hipStream_t stream) {
    const float* q  = (const float*)d_in[0];
    const float* k  = (const float*)d_in[1];
    const float* v  = (const float*)d_in[2];
    const float* Wq = (const float*)d_in[4];
    const float* bq = (const float*)d_in[5];
    const float* Wk = (const float*)d_in[6];
    const float* bk = (const float*)d_in[7];
    const float* Wv = (const float*)d_in[8];
    const float* bv = (const float*)d_in[9];
    const float* Wo = (const float*)d_in[10];
    const float* bo = (const float*)d_in[11];

    const size_t NEL = (size_t)4 * SEQ * DM;  // 8,388,608 elems per buffer
    const size_t WEL = (size_t)DM * DM;       // 1,048,576 elems per weight
    unsigned short* Qp  = (unsigned short*)d_ws;
    unsigned short* Kp  = Qp + NEL;
    unsigned short* Vp  = Kp + NEL;   // attn output Xp
    unsigned short* Vt  = Vp + NEL;
    unsigned short* Wob = Vt + NEL;
    unsigned short* Xp  = Vp;
    unsigned short* Wqb = (unsigned short*)d_out;  // d_out scratch until final GEMM
    unsigned short* Wkb = Wqb + WEL;
    unsigned short* Wvb = Wkb + WEL;

    hipLaunchKernelGGL(cvt_w, dim3(1024, 4), dim3(256), 0, stream, Wq, Wk, Wv, Wo,
                       Wqb, Wkb, Wvb, Wob);
    hipLaunchKernelGGL(gemm_qkv, dim3(1536), dim3(512), 0, stream, q, k, v,
                       Wqb, Wkb, Wvb, bq, bk, bv, Qp, Kp, Vt);
    hipLaunchKernelGGL(attn, dim3(512), dim3(512), 0, stream, Qp, Kp, Vt, Xp);
    hipLaunchKernelGGL(gemm_out, dim3(512), dim3(512), 0, stream, Xp, Wob, bo,
                       (float*)d_out);
}

// Round 26
// 196.948 us; speedup vs baseline: 1.0781x; 1.0781x over previous
//
#include <hip/hip_runtime.h>

#define DM 1024
#define SEQ 2048
#define NH 16
#define DK 64

typedef __bf16 bf16x8 __attribute__((ext_vector_type(8)));
typedef float f32x4 __attribute__((ext_vector_type(4)));

// softmax scale folded into Q: 1/sqrt(64) * log2(e)
#define QSCALE 0.1803368801111244f

__device__ inline unsigned short f2bf(float f) {
    unsigned u = __float_as_uint(f);
    u += 0x7fffu + ((u >> 16) & 1u);
    return (unsigned short)(u >> 16);
}

__device__ inline unsigned pkbf(float lo, float hi) {
    union { __bf16 h[2]; unsigned u; } r;
    r.h[0] = (__bf16)lo; r.h[1] = (__bf16)hi;
    return r.u;
}

// fp32 -> bf16 for the four weight matrices (1M elems each), one dispatch.
__global__ __launch_bounds__(256) void cvt_w(const float* __restrict__ s0,
                                             const float* __restrict__ s1,
                                             const float* __restrict__ s2,
                                             const float* __restrict__ s3,
                                             unsigned short* __restrict__ d0,
                                             unsigned short* __restrict__ d1,
                                             unsigned short* __restrict__ d2,
                                             unsigned short* __restrict__ d3) {
    const float* s;
    unsigned short* d;
    switch (blockIdx.y) {
        case 0: s = s0; d = d0; break;
        case 1: s = s1; d = d1; break;
        case 2: s = s2; d = d2; break;
        default: s = s3; d = d3; break;
    }
    int i = (blockIdx.x * 256 + threadIdx.x) * 4;
    float4 v = *(const float4*)(s + i);
    ushort4 o;
    o.x = f2bf(v.x); o.y = f2bf(v.y); o.z = f2bf(v.z); o.w = f2bf(v.w);
    *(ushort4*)(d + i) = o;
}

// Merged Q/K/V projection GEMM: 1536 blocks (seg = bid>>9), 48KB LDS ->
// 3 blocks/CU, depth-2 A prefetch.
__global__ __launch_bounds__(512) void gemm_qkv(
    const float* __restrict__ Aq, const float* __restrict__ Ak,
    const float* __restrict__ Avv,
    const unsigned short* __restrict__ Wq2, const unsigned short* __restrict__ Wk2,
    const unsigned short* __restrict__ Wv2,
    const float* __restrict__ bq2, const float* __restrict__ bk2,
    const float* __restrict__ bv2,
    unsigned short* __restrict__ Cq, unsigned short* __restrict__ Ck,
    unsigned short* __restrict__ Cvt) {
    __shared__ unsigned short lds_a[128 * 64];
    __shared__ unsigned short lds_w[2][128 * 64];

    const int K = DM, N = DM;
    const int t = threadIdx.x;
    const int lane = t & 63;
    const int w = t >> 6;
    const int wr = w >> 1;
    const int wc = w & 1;
    const int seg = blockIdx.x >> 9;      // 0=Q 1=K 2=V
    const int inner = blockIdx.x & 511;
    const int xcd = inner & 7;
    const int idx = inner >> 3;
    const int rowBase = (xcd * 8 + (idx >> 3)) * 128;
    const int colBase = (idx & 7) * 128;
    const int l15 = lane & 15;
    const int lg = lane >> 4;
    const int ar = t >> 2, aq = t & 3;
    const int NIT = K >> 6;  // 16

    const float* A = seg == 0 ? Aq : (seg == 1 ? Ak : Avv);
    const unsigned short* W = seg == 0 ? Wq2 : (seg == 1 ? Wk2 : Wv2);
    const float* bias = seg == 0 ? bq2 : (seg == 1 ? bk2 : bv2);

    f32x4 acc[2][4] = {};

    auto STAGE_W = [&](int kt, int buf) {
#pragma unroll
        for (int i = 0; i < 2; ++i) {
            const int row = (w * 2 + i) * 8 + (lane >> 3);
            const int sl = lane & 7;
            const unsigned short* src =
                W + (size_t)(colBase + row) * K + kt * 64 + ((sl ^ (row & 7)) * 8);
            __builtin_amdgcn_global_load_lds(src, &lds_w[buf][(w * 2 + i) * 512], 16, 0, 0);
        }
    };
    auto LOADA = [&](int kt, float4* rf) {
        const float* Af = A + (size_t)(rowBase + ar) * K + kt * 64 + aq * 16;
#pragma unroll
        for (int i = 0; i < 4; ++i) rf[i] = *(const float4*)(Af + i * 4);
    };
    auto WRITEA = [&](const float4* rf) {
#pragma unroll
        for (int i = 0; i < 2; ++i) {
            union { __bf16 h[8]; uint4 u; } pk;
            pk.h[0] = (__bf16)rf[2 * i].x; pk.h[1] = (__bf16)rf[2 * i].y;
            pk.h[2] = (__bf16)rf[2 * i].z; pk.h[3] = (__bf16)rf[2 * i].w;
            pk.h[4] = (__bf16)rf[2 * i + 1].x; pk.h[5] = (__bf16)rf[2 * i + 1].y;
            pk.h[6] = (__bf16)rf[2 * i + 1].z; pk.h[7] = (__bf16)rf[2 * i + 1].w;
            *(uint4*)&lds_a[ar * 64 + (((aq * 2 + i) ^ (ar & 7)) * 8)] = pk.u;
        }
    };
    auto COMPUTE = [&](int wbuf) {
#pragma unroll
        for (int kh = 0; kh < 2; ++kh) {
            bf16x8 af[2], wf[4];
#pragma unroll
            for (int m = 0; m < 2; ++m)
                af[m] = *(const bf16x8*)&lds_a[(wr * 32 + m * 16 + l15) * 64 +
                                               (((kh * 4 + lg) ^ (l15 & 7)) * 8)];
#pragma unroll
            for (int n = 0; n < 4; ++n)
                wf[n] = *(const bf16x8*)&lds_w[wbuf][(wc * 64 + n * 16 + l15) * 64 +
                                                    (((kh * 4 + lg) ^ (l15 & 7)) * 8)];
#pragma unroll
            for (int m = 0; m < 2; ++m)
#pragma unroll
                for (int n = 0; n < 4; ++n)
                    acc[m][n] = __builtin_amdgcn_mfma_f32_16x16x32_bf16(af[m], wf[n],
                                                                        acc[m][n], 0, 0, 0);
        }
    };

    float4 ra[4], rb[4];
    STAGE_W(0, 0);
    LOADA(0, ra);
    LOADA(1, rb);
    for (int kt = 0; kt < NIT; kt += 2) {
        if (kt + 1 < NIT) {
            STAGE_W(kt + 1, 1);
            asm volatile("s_waitcnt vmcnt(6)" ::: "memory");
        } else {
            asm volatile("s_waitcnt vmcnt(0)" ::: "memory");
        }
        WRITEA(ra);
        if (kt + 2 < NIT) LOADA(kt + 2, ra);
        asm volatile("s_waitcnt lgkmcnt(0)" ::: "memory");
        __builtin_amdgcn_s_barrier();
        COMPUTE(0);
        __builtin_amdgcn_s_barrier();
        if (kt + 2 < NIT) {
            STAGE_W(kt + 2, 0);
            asm volatile("s_waitcnt vmcnt(6)" ::: "memory");
        } else {
            asm volatile("s_waitcnt vmcnt(0)" ::: "memory");
        }
        WRITEA(rb);
        if (kt + 3 < NIT) LOADA(kt + 3, rb);
        asm volatile("s_waitcnt lgkmcnt(0)" ::: "memory");
        __builtin_amdgcn_s_barrier();
        COMPUTE(1);
        __builtin_amdgcn_s_barrier();
    }

    const float oscale = seg == 0 ? QSCALE : 1.0f;
#pragma unroll
    for (int m = 0; m < 2; ++m) {
        int row = rowBase + wr * 32 + m * 16 + lg * 4;
#pragma unroll
        for (int n = 0; n < 4; ++n) {
            int col = colBase + wc * 64 + n * 16 + l15;
            float bv = bias[col];
            if (seg == 2) {
                const int bh = (row >> 11) * NH + (col >> 6);
                const int dloc = col & 63;
                const int s = row & (SEQ - 1);
                ushort4 o;
                o.x = f2bf(acc[m][n][0] + bv);
                o.y = f2bf(acc[m][n][1] + bv);
                o.z = f2bf(acc[m][n][2] + bv);
                o.w = f2bf(acc[m][n][3] + bv);
                *(ushort4*)(Cvt + ((size_t)bh * DK + dloc) * SEQ + s) = o;
            } else {
                unsigned short* C = seg == 0 ? Cq : Ck;
#pragma unroll
                for (int j = 0; j < 4; ++j)
                    C[(size_t)(row + j) * N + col] = f2bf((acc[m][n][j] + bv) * oscale);
            }
        }
    }
}

// Output GEMM: C[8192,1024]f32 = X bf16 @ Wo bf16^T + bo.  Full dbuf, gload_lds.
__global__ __launch_bounds__(512) void gemm_out(const unsigned short* __restrict__ A,
                                                const unsigned short* __restrict__ W,
                                                const float* __restrict__ bias,
                                                float* __restrict__ C) {
    __shared__ unsigned short lds_a[2][128 * 64];
    __shared__ unsigned short lds_w[2][128 * 64];

    const int K = DM, N = DM;
    const int t = threadIdx.x;
    const int lane = t & 63;
    const int w = t >> 6;
    const int wr = w >> 1;
    const int wc = w & 1;
    const int bid = blockIdx.x;
    const int xcd = bid & 7;
    const int idx = bid >> 3;
    const int rowBase = (xcd * 8 + (idx >> 3)) * 128;
    const int colBase = (idx & 7) * 128;
    const int l15 = lane & 15;
    const int lg = lane >> 4;
    const int NIT = K >> 6;

    f32x4 acc[2][4] = {};

    auto STAGE = [&](const unsigned short* M0, unsigned short* ldsb, int kt) {
#pragma unroll
        for (int i = 0; i < 2; ++i) {
            const int row = (w * 2 + i) * 8 + (lane >> 3);
            const int sl = lane & 7;
            const unsigned short* src =
                M0 + (size_t)row * K + kt * 64 + ((sl ^ (row & 7)) * 8);
            __builtin_amdgcn_global_load_lds(src, ldsb + (w * 2 + i) * 512, 16, 0, 0);
        }
    };
    auto COMPUTE = [&](int buf) {
#pragma unroll
        for (int kh = 0; kh < 2; ++kh) {
            bf16x8 af[2], wf[4];
#pragma unroll
            for (int m = 0; m < 2; ++m)
                af[m] = *(const bf16x8*)&lds_a[buf][(wr * 32 + m * 16 + l15) * 64 +
                                                   (((kh * 4 + lg) ^ (l15 & 7)) * 8)];
#pragma unroll
            for (int n = 0; n < 4; ++n)
                wf[n] = *(const bf16x8*)&lds_w[buf][(wc * 64 + n * 16 + l15) * 64 +
                                                   (((kh * 4 + lg) ^ (l15 & 7)) * 8)];
#pragma unroll
            for (int m = 0; m < 2; ++m)
#pragma unroll
                for (int n = 0; n < 4; ++n)
                    acc[m][n] = __builtin_amdgcn_mfma_f32_16x16x32_bf16(af[m], wf[n],
                                                                        acc[m][n], 0, 0, 0);
        }
    };

    const unsigned short* Arow = A + (size_t)rowBase * K;
    const unsigned short* Wrow = W + (size_t)colBase * K;
    STAGE(Wrow, lds_w[0], 0);
    STAGE(Arow, lds_a[0], 0);
    for (int kt = 0; kt < NIT; ++kt) {
        const int cur = kt & 1;
        if (kt + 1 < NIT) {
            STAGE(Wrow, lds_w[cur ^ 1], kt + 1);
            STAGE(Arow, lds_a[cur ^ 1], kt + 1);
            asm volatile("s_waitcnt vmcnt(4)" ::: "memory");
        } else {
            asm volatile("s_waitcnt vmcnt(0)" ::: "memory");
        }
        __builtin_amdgcn_s_barrier();
        COMPUTE(cur);
        __builtin_amdgcn_s_barrier();
    }

#pragma unroll
    for (int m = 0; m < 2; ++m) {
        int row = rowBase + wr * 32 + m * 16 + lg * 4;
#pragma unroll
        for (int n = 0; n < 4; ++n) {
            int col = colBase + wc * 64 + n * 16 + l15;
            float bv = bias[col];
#pragma unroll
            for (int j = 0; j < 4; ++j)
                C[(size_t)(row + j) * N + col] = acc[m][n][j] + bv;
        }
    }
}

// Flash attention, causal, swapped-operand (r24 best: 4 waves, 64 q-rows).
// K/V staged via global_load_lds DMA (rule #21 pattern: linear dest = wave
// base + lane*16, inverse-swizzled SOURCE column, swizzled read).  P via
// wave-private LDS tile; no online max (exp2 unclamped); ones-row MFMA
// denominator; pair-tasking (qt, 31-qt); XCD-chunked block swizzle.
__global__ __launch_bounds__(256) void attn(const unsigned short* __restrict__ Q,
                                            const unsigned short* __restrict__ K,
                                            const unsigned short* __restrict__ Vt,
                                            unsigned short* __restrict__ X) {
    __shared__ unsigned short k_lds[2][64 * 64];
    __shared__ unsigned short v_lds[2][64 * 64];
    __shared__ unsigned short p_lds[4][16 * 64];  // per-wave P^T tile, swizzled

    const int t = threadIdx.x;
    const int lane = t & 63;
    const int w = t >> 6;
    const int l15 = lane & 15, lg = lane >> 4;

    const int orig = blockIdx.x;
    const int flat = (orig & 7) * 128 + (orig >> 3);
    const int bh = flat >> 4;
    const int pr = flat & 15;
    const int b = bh >> 4, h = bh & 15;

    const unsigned short* Qb = Q + (size_t)b * SEQ * DM + h * DK;
    const unsigned short* Kb = K + (size_t)b * SEQ * DM + h * DK;
    const unsigned short* Vb = Vt + (size_t)bh * DK * SEQ;

    const int xork = (l15 & 7) * 8;
    unsigned short* pl = p_lds[w];

    union { unsigned short us[8]; bf16x8 v; } ou;
#pragma unroll
    for (int i = 0; i < 8; ++i) ou.us[i] = 0x3F80;
    const bf16x8 onesf = ou.v;

    int gp = 0;

    // DMA staging: lane -> row = w*8 + (lane>>3), dest offset = 16*lane from
    // wave base; source col inverse-swizzled so reads stay 0-conflict.
    const int grow = w * 8 + (lane >> 3);
    const int gcol = ((lane & 7) ^ (grow & 7)) * 8;

    auto GLOAD = [&](int kv0, int buf) {
        unsigned short* kl = k_lds[buf];
        unsigned short* vl = v_lds[buf];
        __builtin_amdgcn_global_load_lds(
            Kb + (size_t)(kv0 + grow) * DM + gcol, &kl[w * 512], 16, 0, 0);
        __builtin_amdgcn_global_load_lds(
            Kb + (size_t)(kv0 + 32 + grow) * DM + gcol, &kl[2048 + w * 512], 16, 0, 0);
        __builtin_amdgcn_global_load_lds(
            Vb + (size_t)grow * SEQ + kv0 + gcol, &vl[w * 512], 16, 0, 0);
        __builtin_amdgcn_global_load_lds(
            Vb + (size_t)(32 + grow) * SEQ + kv0 + gcol, &vl[2048 + w * 512], 16, 0, 0);
    };

    GLOAD(0, 0);  // task-0 tile-0

    for (int task = 0; task < 2; ++task) {
        const int qt = task ? 31 - pr : pr;
        const int qrow0 = qt * 64 + w * 16;
        const int qg = qrow0 + l15;

        const bf16x8 qf0 = *(const bf16x8*)(Qb + (size_t)(qrow0 + l15) * DM + lg * 8);
        const bf16x8 qf1 = *(const bf16x8*)(Qb + (size_t)(qrow0 + l15) * DM + lg * 8 + 32);

        f32x4 acc[4] = {};
        f32x4 accS = {};
        const int nt = qt + 1;

        for (int tile = 0; tile < nt; ++tile) {
            const int kv0 = tile << 6;
            unsigned short* kl = k_lds[gp & 1];
            unsigned short* vl = v_lds[gp & 1];
            // my DMA writes for THIS tile done; barrier makes all waves' visible
            asm volatile("s_waitcnt vmcnt(0)" ::: "memory");
            __syncthreads();

            if (tile + 1 < nt)
                GLOAD((tile + 1) << 6, (gp + 1) & 1);
            else if (task == 0)
                GLOAD(0, (gp + 1) & 1);  // prefetch task-1 tile-0

            f32x4 st[4];
#pragma unroll
            for (int s = 0; s < 4; ++s) {
                const int rb2 = (s * 16 + l15) * 64;
                bf16x8 ka = *(const bf16x8*)&kl[rb2 + ((lg * 8) ^ xork)];
                bf16x8 kb2 = *(const bf16x8*)&kl[rb2 + ((32 + lg * 8) ^ xork)];
                f32x4 z = {};
                z = __builtin_amdgcn_mfma_f32_16x16x32_bf16(ka, qf0, z, 0, 0, 0);
                st[s] = __builtin_amdgcn_mfma_f32_16x16x32_bf16(kb2, qf1, z, 0, 0, 0);
            }

            bf16x8 vf[4][2];
#pragma unroll
            for (int d = 0; d < 4; ++d) {
                const int rb2 = (d * 16 + l15) * 64;
                vf[d][0] = *(const bf16x8*)&vl[rb2 + ((lg * 8) ^ xork)];
                vf[d][1] = *(const bf16x8*)&vl[rb2 + ((32 + lg * 8) ^ xork)];
            }

            // P = exp2(score); masked lanes get 0
            float ps[16];
            if (kv0 + 63 > qrow0) {  // diagonal: apply causal mask
#pragma unroll
                for (int s = 0; s < 4; ++s)
#pragma unroll
                    for (int j = 0; j < 4; ++j) {
                        const bool ok = kv0 + s * 16 + 4 * lg + j <= qg;
                        ps[s * 4 + j] = ok ? exp2f(st[s][j]) : 0.0f;
                    }
            } else {
#pragma unroll
                for (int s = 0; s < 4; ++s)
#pragma unroll
                    for (int j = 0; j < 4; ++j)
                        ps[s * 4 + j] = exp2f(st[s][j]);
            }

            // write P[q=l15][kv] to wave-private LDS (slot-swizzled), no barrier
#pragma unroll
            for (int s = 0; s < 4; ++s) {
                uint2 pk;
                pk.x = pkbf(ps[s * 4 + 0], ps[s * 4 + 1]);
                pk.y = pkbf(ps[s * 4 + 2], ps[s * 4 + 3]);
                const int slot = (s * 2 + (lg >> 1)) ^ (l15 & 7);
                *(uint2*)&pl[l15 * 64 + slot * 8 + (lg & 1) * 4] = pk;
            }
            bf16x8 pf[2];
#pragma unroll
            for (int hh = 0; hh < 2; ++hh)
                pf[hh] = *(const bf16x8*)&pl[l15 * 64 + (((hh * 4 + lg) ^ (l15 & 7)) * 8)];

#pragma unroll
            for (int d = 0; d < 4; ++d) {
                acc[d] = __builtin_amdgcn_mfma_f32_16x16x32_bf16(vf[d][0], pf[0], acc[d], 0, 0, 0);
                acc[d] = __builtin_amdgcn_mfma_f32_16x16x32_bf16(vf[d][1], pf[1], acc[d], 0, 0, 0);
            }
            accS = __builtin_amdgcn_mfma_f32_16x16x32_bf16(onesf, pf[0], accS, 0, 0, 0);
            accS = __builtin_amdgcn_mfma_f32_16x16x32_bf16(onesf, pf[1], accS, 0, 0, 0);
            gp++;
        }

        const float inv = 1.0f / accS[0];
#pragma unroll
        for (int d = 0; d < 4; ++d) {
            ushort4 o;
            o.x = f2bf(acc[d][0] * inv);
            o.y = f2bf(acc[d][1] * inv);
            o.z = f2bf(acc[d][2] * inv);
            o.w = f2bf(acc[d][3] * inv);
            *(ushort4*)&X[(size_t)(b * SEQ + qg) * DM + h * DK + d * 16 + 4 * lg] = o;
        }
    }
}

extern "C" void kernel_launch(void* const* d_in, const int* in_sizes, int n_in,
                              void* d_out, int out_size, void* d_ws, size_t ws_size,
                              hipStream_t stream) {
    const float* q  = (const float*)d_in[0];
    const float* k  = (const float*)d_in[1];
    const float* v  = (const float*)d_in[2];
    const float* Wq = (const float*)d_in[4];
    const float* bq = (const float*)d_in[5];
    const float* Wk = (const float*)d_in[6];
    const float* bk = (const float*)d_in[7];
    const float* Wv = (const float*)d_in[8];
    const float* bv = (const float*)d_in[9];
    const float* Wo = (const float*)d_in[10];
    const float* bo = (const float*)d_in[11];

    const size_t NEL = (size_t)4 * SEQ * DM;  // 8,388,608 elems per buffer
    const size_t WEL = (size_t)DM * DM;       // 1,048,576 elems per weight
    unsigned short* Qp  = (unsigned short*)d_ws;
    unsigned short* Kp  = Qp + NEL;
    unsigned short* Vp  = Kp + NEL;   // attn output Xp
    unsigned short* Vt  = Vp + NEL;
    unsigned short* Wob = Vt + NEL;
    unsigned short* Xp  = Vp;
    unsigned short* Wqb = (unsigned short*)d_out;  // d_out scratch until final GEMM
    unsigned short* Wkb = Wqb + WEL;
    unsigned short* Wvb = Wkb + WEL;

    hipLaunchKernelGGL(cvt_w, dim3(1024, 4), dim3(256), 0, stream, Wq, Wk, Wv, Wo,
                       Wqb, Wkb, Wvb, Wob);
    hipLaunchKernelGGL(gemm_qkv, dim3(1536), dim3(512), 0, stream, q, k, v,
                       Wqb, Wkb, Wvb, bq, bk, bv, Qp, Kp, Vt);
    hipLaunchKernelGGL(attn, dim3(1024), dim3(256), 0, stream, Qp, Kp, Vt, Xp);
    hipLaunchKernelGGL(gemm_out, dim3(512), dim3(512), 0, stream, Xp, Wob, bo,
                       (float*)d_out);
}